// Round 7
// baseline (759.455 us; speedup 1.0000x reference)
//
#include <hip/hip_runtime.h>

#define B_ 32
#define T_ 1024
#define C_ 384
#define MAXLEN_ 2048
#define NBINS_ 255
#define WPK1 442368          /* 36*4*6*512 packed bf16 elems per weight */
#define BTC  (32 * 1024 * 384)
#define ARS 396              /* A-tile row stride in bf16 */

typedef __attribute__((ext_vector_type(8))) short short8v;   // 8 bf16 = 4 VGPRs
typedef __attribute__((ext_vector_type(4))) float floatx4;

__device__ __forceinline__ unsigned short f2bf(float f) {
    unsigned u = __float_as_uint(f);
    u += 0x7fffu + ((u >> 16) & 1u);   // RNE
    return (unsigned short)(u >> 16);
}

struct CvP {
    const float* xf;              // layer1 input (fp32 x)
    const unsigned short* xb;     // layer2 input base (h1b), + p*BTC
    const unsigned short* wpk;    // + p*WPK1
    const float* bias[3];
    const float* gamma[3];
    const float* beta[3];
    const float* wo[3];
    const float* bo[3];
    unsigned short* hout;         // layer1 out, + p*BTC
    float* pred[3];               // layer2 out
    const float* pbins;           // pitch-emb fusion (layer1, p==2)
    const float* pemb;
    const float* ptgt;
    int final_flag;
};

// ---------------------------------------------------------------------------
// 3-predictor fused conv1d(K=3,SAME)+bias+relu+LN[+projection], bf16 MFMA.
// Block: 512 thr = 8 waves; tile 64 rows x 384 cols; wave owns 48 cols.
// Per-wave registers: acc 48 + bA 12 + bB 12 + afrag 16 ~= 88 (+addr ~115)
// -> fits 128 = honest __launch_bounds__(512,4) -> 16 waves/CU, NO spill
// (R6 lesson: 180 regs under a 170 bound spilled 29 MB to scratch).
// Distance-2 B prefetch from global fragment-major wpk; A-tile in LDS.
// ---------------------------------------------------------------------------
__global__ __launch_bounds__(512, 4) void conv_mfma3(CvP P)
{
    __shared__ unsigned short As[66 * ARS];   // 52.3 KB
    float* rsum = (float*)As;                 // [8][64] aliased (post-K-loop)
    float* rsq  = rsum + 512;

    const int tid  = threadIdx.x;
    const int wave = tid >> 6;      // col group 0..7 (48 cols each)
    const int lane = tid & 63;
    const int lq   = lane >> 4;
    const int ln   = lane & 15;
    const int p    = blockIdx.x >> 9;       // predictor 0..2
    const int bi   = blockIdx.x & 511;      // tile 0..511
    const int b    = bi >> 4;
    const int t0   = (bi & 15) << 6;        // 64-row tiles
    const int nb   = wave * 48;

    // B fragment base: wpk layout [r][wv4][nt6][512]; wave w covers old
    // (wv = w>>1, ntold = (w&1)*3 + nt)
    const unsigned short* bbase = P.wpk + (size_t)p * WPK1
        + (wave >> 1) * 3072 + (wave & 1) * 1536 + (size_t)lane * 8;
    short8v bA[3], bB[3];
#pragma unroll
    for (int nt = 0; nt < 3; ++nt) {
        bA[nt] = *(const short8v*)(bbase + (nt << 9));
        bB[nt] = *(const short8v*)(bbase + 12288 + (nt << 9));
    }

    // ---- stage A-tile rows t0-1 .. t0+64 (zero halo) ----
    if (!P.final_flag) {
        const bool fuse_emb = (p == 2);
        for (int i = tid; i < 66 * 48; i += 512) {
            const int row = i / 48;
            const int c   = i - row * 48;
            const int t   = t0 - 1 + row;
            short8v v = (short8v){0,0,0,0,0,0,0,0};
            if ((unsigned)t < (unsigned)T_) {
                const float* sp = P.xf + ((size_t)(b << 10) + t) * C_ + c * 8;
                float f[8];
                *(float4*)&f[0] = *(const float4*)sp;
                *(float4*)&f[4] = *(const float4*)(sp + 4);
                if (fuse_emb) {
                    const float tg = P.ptgt[(b << 10) + t];
                    int lo = 0, hi = NBINS_;
                    while (lo < hi) {
                        const int mid = (lo + hi) >> 1;
                        if (P.pbins[mid] < tg) lo = mid + 1; else hi = mid;
                    }
                    const float* er = P.pemb + (size_t)lo * C_ + c * 8;
#pragma unroll
                    for (int j = 0; j < 8; ++j) f[j] += er[j];
                }
#pragma unroll
                for (int j = 0; j < 8; ++j) v[j] = (short)f2bf(f[j]);
            }
            *(short8v*)&As[row * ARS + c * 8] = v;
        }
    } else {
        const unsigned short* xb = P.xb + (size_t)p * BTC;
        for (int i = tid; i < 66 * 48; i += 512) {
            const int row = i / 48;
            const int c   = i - row * 48;
            const int t   = t0 - 1 + row;
            short8v v = (short8v){0,0,0,0,0,0,0,0};
            if ((unsigned)t < (unsigned)T_)
                v = *(const short8v*)(xb + ((size_t)(b << 10) + t) * C_ + c * 8);
            *(short8v*)&As[row * ARS + c * 8] = v;
        }
    }
    __syncthreads();

    floatx4 acc[12];
#pragma unroll
    for (int i = 0; i < 12; ++i) acc[i] = (floatx4){0.f, 0.f, 0.f, 0.f};

    const unsigned short* abase = &As[ln * ARS + lq * 8];
    const unsigned short* bpA = bbase + 2 * 12288;
    const unsigned short* bpB = bbase + 3 * 12288;

#pragma unroll
    for (int kc = 0; kc < 3; ++kc) {
#pragma unroll
        for (int h2 = 0; h2 < 6; ++h2) {
            const int hb = h2 * 64;
            const int r  = kc * 12 + h2 * 2;
            // even step: consume bA
            {
                short8v afrag[4];
#pragma unroll
                for (int mt = 0; mt < 4; ++mt)
                    afrag[mt] = *(const short8v*)(abase + (mt * 16 + kc) * ARS + hb);
#pragma unroll
                for (int mt = 0; mt < 4; ++mt)
#pragma unroll
                    for (int nt = 0; nt < 3; ++nt)
                        acc[mt * 3 + nt] = __builtin_amdgcn_mfma_f32_16x16x32_bf16(
                            afrag[mt], bA[nt], acc[mt * 3 + nt], 0, 0, 0);
                if (r + 2 < 36) {
#pragma unroll
                    for (int nt = 0; nt < 3; ++nt)
                        bA[nt] = *(const short8v*)(bpA + (nt << 9));
                    bpA += 24576;
                }
            }
            // odd step: consume bB
            {
                short8v afrag[4];
#pragma unroll
                for (int mt = 0; mt < 4; ++mt)
                    afrag[mt] = *(const short8v*)(abase + (mt * 16 + kc) * ARS + hb + 32);
#pragma unroll
                for (int mt = 0; mt < 4; ++mt)
#pragma unroll
                    for (int nt = 0; nt < 3; ++nt)
                        acc[mt * 3 + nt] = __builtin_amdgcn_mfma_f32_16x16x32_bf16(
                            afrag[mt], bB[nt], acc[mt * 3 + nt], 0, 0, 0);
                if (r + 3 < 36) {
#pragma unroll
                    for (int nt = 0; nt < 3; ++nt)
                        bB[nt] = *(const short8v*)(bpB + (nt << 9));
                    bpB += 24576;
                }
            }
        }
    }
    __syncthreads();   // all As reads done before aliasing it as rsum/rsq

    // ---- epilogue: bias+relu, LN over 384 cols/row (8 waves x 48 cols) ----
    float bcol[3], gcol[3], becol[3], wcol[3];
#pragma unroll
    for (int nt = 0; nt < 3; ++nt) {
        const int col = nb + nt * 16 + ln;
        bcol[nt]  = P.bias[p][col];
        gcol[nt]  = P.gamma[p][col];
        becol[nt] = P.beta[p][col];
        wcol[nt]  = P.final_flag ? P.wo[p][col] : 0.f;
    }

#pragma unroll
    for (int mt = 0; mt < 4; ++mt) {
#pragma unroll
        for (int rg = 0; rg < 4; ++rg) {
            float s = 0.f, q = 0.f;
#pragma unroll
            for (int nt = 0; nt < 3; ++nt) {
                float v = acc[mt * 3 + nt][rg] + bcol[nt];
                v = v > 0.f ? v : 0.f;
                acc[mt * 3 + nt][rg] = v;
                s += v; q += v * v;
            }
#pragma unroll
            for (int off = 1; off < 16; off <<= 1) {
                s += __shfl_xor(s, off, 64);
                q += __shfl_xor(q, off, 64);
            }
            if (ln == mt * 4 + rg) {
                rsum[wave * 64 + mt * 16 + lq * 4 + rg] = s;
                rsq [wave * 64 + mt * 16 + lq * 4 + rg] = q;
            }
        }
    }
    __syncthreads();

    float mean_[16], rstd_[16];
#pragma unroll
    for (int mt = 0; mt < 4; ++mt) {
#pragma unroll
        for (int rg = 0; rg < 4; ++rg) {
            const int row = mt * 16 + lq * 4 + rg;
            float s = 0.f, q = 0.f;
#pragma unroll
            for (int w = 0; w < 8; ++w) { s += rsum[w * 64 + row]; q += rsq[w * 64 + row]; }
            const float m = s * (1.f / 384.f);
            const float var = q * (1.f / 384.f) - m * m;
            mean_[mt * 4 + rg] = m;
            rstd_[mt * 4 + rg] = rsqrtf(var + 1e-5f);
        }
    }

    if (!P.final_flag) {
        unsigned short* hout = P.hout + (size_t)p * BTC;
#pragma unroll
        for (int mt = 0; mt < 4; ++mt)
#pragma unroll
            for (int rg = 0; rg < 4; ++rg) {
                const float m = mean_[mt * 4 + rg], rs = rstd_[mt * 4 + rg];
                const int grow = (bi << 6) + mt * 16 + lq * 4 + rg;
#pragma unroll
                for (int nt = 0; nt < 3; ++nt) {
                    const float v = (acc[mt * 3 + nt][rg] - m) * rs * gcol[nt] + becol[nt];
                    hout[(size_t)grow * C_ + nb + nt * 16 + ln] = f2bf(v);
                }
            }
    } else {
        __syncthreads();                       // rsum about to be reused
#pragma unroll
        for (int mt = 0; mt < 4; ++mt) {
#pragma unroll
            for (int rg = 0; rg < 4; ++rg) {
                const float m = mean_[mt * 4 + rg], rs = rstd_[mt * 4 + rg];
                float pr = 0.f;
#pragma unroll
                for (int nt = 0; nt < 3; ++nt)
                    pr += ((acc[mt * 3 + nt][rg] - m) * rs * gcol[nt] + becol[nt]) * wcol[nt];
#pragma unroll
                for (int off = 1; off < 16; off <<= 1)
                    pr += __shfl_xor(pr, off, 64);
                if (ln == mt * 4 + rg)
                    rsum[wave * 64 + mt * 16 + lq * 4 + rg] = pr;
            }
        }
        __syncthreads();
        if (tid < 64) {
            float s = P.bo[p][0];
#pragma unroll
            for (int w = 0; w < 8; ++w) s += rsum[w * 64 + tid];
            P.pred[p][(bi << 6) + tid] = s;
        }
    }
}

// w (1152,384) fp32 -> wpk fragment-major bf16 (same layout as R5/R6)
__global__ __launch_bounds__(256) void pack_w_kernel(
    const float* __restrict__ s0, const float* __restrict__ s1,
    const float* __restrict__ s2, const float* __restrict__ s3,
    const float* __restrict__ s4, const float* __restrict__ s5,
    unsigned short* __restrict__ dst)
{
    const int wsel = blockIdx.y;
    const float* src = wsel == 0 ? s0 : wsel == 1 ? s1 : wsel == 2 ? s2
                     : wsel == 3 ? s3 : wsel == 4 ? s4 : s5;
    const int o = blockIdx.x * 256 + threadIdx.x;   // 442368
    const int r    = o / 12288;
    const int rem  = o - r * 12288;
    const int wv   = rem / 3072;
    const int rem2 = rem - wv * 3072;
    const int nt   = rem2 >> 9;
    const int li   = rem2 & 511;
    const int lane = li >> 3;
    const int j    = li & 7;
    const int n = wv * 96 + nt * 16 + (lane & 15);
    const int k = ((lane >> 4) << 3) + j;
    dst[(size_t)wsel * WPK1 + o] = f2bf(src[(size_t)(r * 32 + k) * C_ + n]);
}

// Fused: per-batch cumsum of duration + per-frame packed gather index
// pk = t | plo<<10 | elo<<19 (or -1 if frame >= total); mel_len.
__global__ __launch_bounds__(256) void cumsum_idx_kernel(
    const int* __restrict__ dur,
    const float* __restrict__ pbins, const float* __restrict__ ptgt,
    const float* __restrict__ ebins, const float* __restrict__ etgt,
    int* __restrict__ xidx, float* __restrict__ mel_len)
{
    __shared__ int cs[T_];          // inclusive cumsum, this batch row
    __shared__ int part[256];
    __shared__ float pb[NBINS_], eb[NBINS_];
    const int b = blockIdx.x;
    const int tid = threadIdx.x;
    if (tid < NBINS_) { pb[tid] = pbins[tid]; eb[tid] = ebins[tid]; }
    int l[4];
    int s = 0;
#pragma unroll
    for (int i = 0; i < 4; ++i) { l[i] = dur[(b << 10) + tid * 4 + i]; s += l[i]; }
    part[tid] = s;
    __syncthreads();
    for (int off = 1; off < 256; off <<= 1) {
        int u = 0;
        if (tid >= off) u = part[tid - off];
        __syncthreads();
        part[tid] += u;
        __syncthreads();
    }
    const int incl = part[tid];
    int run = incl - s;
#pragma unroll
    for (int i = 0; i < 4; ++i) {
        run += l[i];
        cs[tid * 4 + i] = run;
    }
    if (tid == 255) mel_len[b] = (float)incl;
    __syncthreads();
    const int total = cs[T_ - 1];
    for (int f = tid; f < MAXLEN_; f += 256) {
        int pk = -1;
        if (f < total) {
            int lo = 0, hi = T_;
            while (lo < hi) {
                const int mid = (lo + hi) >> 1;
                if (cs[mid] <= f) lo = mid + 1; else hi = mid;
            }
            const int t = lo > T_ - 1 ? T_ - 1 : lo;
            const int row = (b << 10) + t;
            const float ptg = ptgt[row];
            int plo = 0, phi = NBINS_;
            while (plo < phi) {
                const int mid = (plo + phi) >> 1;
                if (pb[mid] < ptg) plo = mid + 1; else phi = mid;
            }
            const float etg = etgt[row];
            int elo = 0, ehi = NBINS_;
            while (elo < ehi) {
                const int mid = (elo + ehi) >> 1;
                if (eb[mid] < etg) elo = mid + 1; else ehi = mid;
            }
            pk = t | (plo << 10) | (elo << 19);
        }
        xidx[(b << 11) + f] = pk;
    }
}

// out[b,frame,:] = pk<0 ? 0 : x[b,t,:] + pemb[plo] + eemb[elo]  (fp32 exact)
__global__ __launch_bounds__(256) void length_reg_kernel(
    const float* __restrict__ x, const int* __restrict__ xidx,
    const float* __restrict__ pemb, const float* __restrict__ eemb,
    float* __restrict__ out)
{
    const int g    = blockIdx.x * 256 + threadIdx.x;  // B*2048*96
    const int c4   = g % 96;
    const int rest = g / 96;
    const int frame = rest & (MAXLEN_ - 1);
    const int b     = rest >> 11;
    const int pk = xidx[(b << 11) + frame];
    float4 v = make_float4(0.f, 0.f, 0.f, 0.f);
    if (pk >= 0) {
        const int t   = pk & 1023;
        const int plo = (pk >> 10) & 511;
        const int elo = (pk >> 19) & 511;
        v = *(const float4*)(x + ((size_t)(b << 10) + t) * C_ + c4 * 4);
        const float4 pe = *(const float4*)(pemb + (size_t)plo * C_ + c4 * 4);
        const float4 ee = *(const float4*)(eemb + (size_t)elo * C_ + c4 * 4);
        v.x += pe.x + ee.x; v.y += pe.y + ee.y;
        v.z += pe.z + ee.z; v.w += pe.w + ee.w;
    }
    *(float4*)(out + (size_t)g * 4) = v;
}

extern "C" void kernel_launch(void* const* d_in, const int* in_sizes, int n_in,
                              void* d_out, int out_size, void* d_ws, size_t ws_size,
                              hipStream_t stream)
{
    const float* x        = (const float*)d_in[0];
    const int*   duration = (const int*)d_in[2];
    const float* P[3][10];
    for (int p = 0; p < 3; ++p)
        for (int q = 0; q < 10; ++q)
            P[p][q] = (const float*)d_in[4 + p * 10 + q];
    const float* pitch_bins    = (const float*)d_in[34];
    const float* energy_bins   = (const float*)d_in[35];
    const float* pitch_emb     = (const float*)d_in[36];
    const float* energy_emb    = (const float*)d_in[37];
    const float* pitch_target  = (const float*)d_in[38];
    const float* energy_target = (const float*)d_in[39];

    float* out_x      = (float*)d_out;                       // (B,2048,384)
    float* out_pitch  = out_x + (size_t)B_ * MAXLEN_ * C_;
    float* out_energy = out_pitch + B_ * T_;
    float* out_logdur = out_energy + B_ * T_;
    float* out_mellen = out_logdur + B_ * T_;

    // h1b (3 predictors, bf16) lives in the x_out region (75.5 MB of 100.7 MB,
    // dead before length_reg writes it)
    unsigned short* h1b = (unsigned short*)out_x;

    unsigned short* wpk = (unsigned short*)d_ws;             // 6*WPK1 bf16
    int* xidx = (int*)(wpk + (size_t)6 * WPK1);              // B*2048 ints

    const dim3 blk(256);

    pack_w_kernel<<<dim3(1728, 6), blk, 0, stream>>>(
        P[0][0], P[0][4], P[1][0], P[1][4], P[2][0], P[2][4], wpk);

    CvP P1;
    P1.xf = x; P1.xb = nullptr; P1.wpk = wpk;
    for (int p = 0; p < 3; ++p) {
        P1.bias[p]  = P[p][1];
        P1.gamma[p] = P[p][2];
        P1.beta[p]  = P[p][3];
        P1.wo[p]    = nullptr;
        P1.bo[p]    = nullptr;
        P1.pred[p]  = nullptr;
    }
    P1.hout = h1b;
    P1.pbins = pitch_bins; P1.pemb = pitch_emb; P1.ptgt = pitch_target;
    P1.final_flag = 0;

    CvP P2;
    P2.xf = nullptr; P2.xb = h1b; P2.wpk = wpk + (size_t)3 * WPK1;
    for (int p = 0; p < 3; ++p) {
        P2.bias[p]  = P[p][5];
        P2.gamma[p] = P[p][6];
        P2.beta[p]  = P[p][7];
        P2.wo[p]    = P[p][8];
        P2.bo[p]    = P[p][9];
    }
    P2.pred[0] = out_logdur; P2.pred[1] = out_pitch; P2.pred[2] = out_energy;
    P2.hout = nullptr;
    P2.pbins = nullptr; P2.pemb = nullptr; P2.ptgt = nullptr;
    P2.final_flag = 1;

    conv_mfma3<<<1536, dim3(512), 0, stream>>>(P1);
    conv_mfma3<<<1536, dim3(512), 0, stream>>>(P2);

    cumsum_idx_kernel<<<B_, blk, 0, stream>>>(
        duration, pitch_bins, pitch_target, energy_bins, energy_target,
        xidx, out_mellen);
    length_reg_kernel<<<24576, blk, 0, stream>>>(
        x, xidx, pitch_emb, energy_emb, out_x);
}

// Round 8
// 465.273 us; speedup vs baseline: 1.6323x; 1.6323x over previous
//
#include <hip/hip_runtime.h>

#define B_ 32
#define T_ 1024
#define C_ 384
#define MAXLEN_ 2048
#define NBINS_ 255
#define WPK1 442368          /* 36*4*6*512 packed bf16 elems per weight */
#define BTC  (32 * 1024 * 384)
#define ARS 392              /* A-tile row stride in bf16 (R5 exact) */

typedef __attribute__((ext_vector_type(8))) short short8v;   // 8 bf16 = 4 VGPRs
typedef __attribute__((ext_vector_type(4))) float floatx4;

__device__ __forceinline__ unsigned short f2bf(float f) {
    unsigned u = __float_as_uint(f);
    u += 0x7fffu + ((u >> 16) & 1u);   // RNE
    return (unsigned short)(u >> 16);
}

struct CvP {
    const float* xf;              // layer1 input (fp32 x)
    const unsigned short* xb;     // layer2 input base (h1b), + p*BTC
    const unsigned short* wpk;    // + p*WPK1
    const float* bias[3];
    const float* gamma[3];
    const float* beta[3];
    const float* wo[3];
    const float* bo[3];
    unsigned short* hout;         // layer1 out, + p*BTC
    float* pred[3];               // layer2 out
    const float* pbins;           // pitch-emb fusion (layer1, p==2)
    const float* pemb;
    const float* ptgt;
    int final_flag;
};

// ---------------------------------------------------------------------------
// R5-exact conv kernel (best measured: 143 us/dispatch, no spill).
// 3-predictor fused conv1d(K=3,SAME)+bias+relu+LN[+projection], bf16 MFMA.
// Block: 256 thr = 4 waves, tile 64 rows x 384 cols; wave owns 96 cols.
// A-tile in LDS (staged once); B from global fragment-major wpk with
// distance-2 register prefetch; K-loop fully unrolled, offsets immediate.
// NOTE (R6/R7 lesson): do NOT tighten launch_bounds past 2 waves/SIMD —
// acc 96 AGPR + ~112 arch VGPR = 208 regs; any bound <=170 spills 100+ MB.
// ---------------------------------------------------------------------------
__global__ __launch_bounds__(256, 2) void conv_mfma3(CvP P)
{
    __shared__ unsigned short As[66 * ARS];   // 51.7 KB
    float* rsum = (float*)As;                 // [4][64] aliased (post-K-loop)
    float* rsq  = rsum + 256;

    const int tid  = threadIdx.x;
    const int wave = tid >> 6;      // col group 0..3
    const int lane = tid & 63;
    const int lq   = lane >> 4;
    const int ln   = lane & 15;
    const int p    = blockIdx.x >> 9;       // predictor 0..2
    const int bi   = blockIdx.x & 511;      // tile 0..511
    const int b    = bi >> 4;
    const int t0   = (bi & 15) << 6;        // 64-row tiles
    const int nb   = wave * 96;

    // ---- B prefetch, steps 0 and 1 (issued before staging to hide latency)
    const unsigned short* bbase =
        P.wpk + (size_t)p * WPK1 + wave * 3072 + (size_t)lane * 8;
    short8v bA[6], bB[6];
#pragma unroll
    for (int nt = 0; nt < 6; ++nt) {
        bA[nt] = *(const short8v*)(bbase + (nt << 9));
        bB[nt] = *(const short8v*)(bbase + 12288 + (nt << 9));
    }

    // ---- stage A-tile rows t0-1 .. t0+64 (zero halo) ----
    if (!P.final_flag) {
        // layer1: cast fp32 x -> bf16; p==2 additionally adds pitch emb
        const bool fuse_emb = (p == 2);
        for (int i = tid; i < 66 * 48; i += 256) {
            const int row = i / 48;
            const int c   = i - row * 48;
            const int t   = t0 - 1 + row;
            short8v v = (short8v){0,0,0,0,0,0,0,0};
            if ((unsigned)t < (unsigned)T_) {
                const float* sp = P.xf + ((size_t)(b << 10) + t) * C_ + c * 8;
                float f[8];
                *(float4*)&f[0] = *(const float4*)sp;
                *(float4*)&f[4] = *(const float4*)(sp + 4);
                if (fuse_emb) {
                    const float tg = P.ptgt[(b << 10) + t];
                    int lo = 0, hi = NBINS_;
                    while (lo < hi) {
                        const int mid = (lo + hi) >> 1;
                        if (P.pbins[mid] < tg) lo = mid + 1; else hi = mid;
                    }
                    const float* er = P.pemb + (size_t)lo * C_ + c * 8;
#pragma unroll
                    for (int j = 0; j < 8; ++j) f[j] += er[j];
                }
#pragma unroll
                for (int j = 0; j < 8; ++j) v[j] = (short)f2bf(f[j]);
            }
            *(short8v*)&As[row * ARS + c * 8] = v;
        }
    } else {
        const unsigned short* xb = P.xb + (size_t)p * BTC;
        for (int i = tid; i < 66 * 48; i += 256) {
            const int row = i / 48;
            const int c   = i - row * 48;
            const int t   = t0 - 1 + row;
            short8v v = (short8v){0,0,0,0,0,0,0,0};
            if ((unsigned)t < (unsigned)T_)
                v = *(const short8v*)(xb + ((size_t)(b << 10) + t) * C_ + c * 8);
            *(short8v*)&As[row * ARS + c * 8] = v;
        }
    }
    __syncthreads();

    floatx4 acc[24];
#pragma unroll
    for (int i = 0; i < 24; ++i) acc[i] = (floatx4){0.f, 0.f, 0.f, 0.f};

    // single LDS vaddr; all K-loop offsets are compile-time immediates
    const unsigned short* abase = &As[ln * ARS + lq * 8];
    const unsigned short* bpA = bbase + 2 * 12288;
    const unsigned short* bpB = bbase + 3 * 12288;

#pragma unroll
    for (int kc = 0; kc < 3; ++kc) {
#pragma unroll
        for (int h2 = 0; h2 < 6; ++h2) {
            const int hb = h2 * 64;
            const int r  = kc * 12 + h2 * 2;
            // -------- even step: consume bA --------
            {
                short8v afrag[4];
#pragma unroll
                for (int mt = 0; mt < 4; ++mt)
                    afrag[mt] = *(const short8v*)(abase + (mt * 16 + kc) * ARS + hb);
#pragma unroll
                for (int mt = 0; mt < 4; ++mt)
#pragma unroll
                    for (int nt = 0; nt < 6; ++nt)
                        acc[mt * 6 + nt] = __builtin_amdgcn_mfma_f32_16x16x32_bf16(
                            afrag[mt], bA[nt], acc[mt * 6 + nt], 0, 0, 0);
                if (r + 2 < 36) {
#pragma unroll
                    for (int nt = 0; nt < 6; ++nt)
                        bA[nt] = *(const short8v*)(bpA + (nt << 9));
                    bpA += 24576;
                }
            }
            // -------- odd step: consume bB --------
            {
                short8v afrag[4];
#pragma unroll
                for (int mt = 0; mt < 4; ++mt)
                    afrag[mt] = *(const short8v*)(abase + (mt * 16 + kc) * ARS + hb + 32);
#pragma unroll
                for (int mt = 0; mt < 4; ++mt)
#pragma unroll
                    for (int nt = 0; nt < 6; ++nt)
                        acc[mt * 6 + nt] = __builtin_amdgcn_mfma_f32_16x16x32_bf16(
                            afrag[mt], bB[nt], acc[mt * 6 + nt], 0, 0, 0);
                if (r + 3 < 36) {
#pragma unroll
                    for (int nt = 0; nt < 6; ++nt)
                        bB[nt] = *(const short8v*)(bpB + (nt << 9));
                    bpB += 24576;
                }
            }
        }
    }
    __syncthreads();   // all As reads done before aliasing it as rsum/rsq

    // ---- epilogue: bias+relu, LN over 384 cols/row ----
    float bcol[6], gcol[6], becol[6], wcol[6];
#pragma unroll
    for (int nt = 0; nt < 6; ++nt) {
        const int col = nb + nt * 16 + ln;
        bcol[nt]  = P.bias[p][col];
        gcol[nt]  = P.gamma[p][col];
        becol[nt] = P.beta[p][col];
        wcol[nt]  = P.final_flag ? P.wo[p][col] : 0.f;
    }

#pragma unroll
    for (int mt = 0; mt < 4; ++mt) {
#pragma unroll
        for (int rg = 0; rg < 4; ++rg) {
            float s = 0.f, q = 0.f;
#pragma unroll
            for (int nt = 0; nt < 6; ++nt) {
                float v = acc[mt * 6 + nt][rg] + bcol[nt];
                v = v > 0.f ? v : 0.f;
                acc[mt * 6 + nt][rg] = v;
                s += v; q += v * v;
            }
#pragma unroll
            for (int off = 1; off < 16; off <<= 1) {
                s += __shfl_xor(s, off, 64);
                q += __shfl_xor(q, off, 64);
            }
            if (ln == mt * 4 + rg) {
                rsum[wave * 64 + mt * 16 + lq * 4 + rg] = s;
                rsq [wave * 64 + mt * 16 + lq * 4 + rg] = q;
            }
        }
    }
    __syncthreads();

    float mean_[16], rstd_[16];
#pragma unroll
    for (int mt = 0; mt < 4; ++mt) {
#pragma unroll
        for (int rg = 0; rg < 4; ++rg) {
            const int row = mt * 16 + lq * 4 + rg;
            const float s = rsum[row] + rsum[64 + row] + rsum[128 + row] + rsum[192 + row];
            const float q = rsq[row] + rsq[64 + row] + rsq[128 + row] + rsq[192 + row];
            const float m = s * (1.f / 384.f);
            const float var = q * (1.f / 384.f) - m * m;
            mean_[mt * 4 + rg] = m;
            rstd_[mt * 4 + rg] = rsqrtf(var + 1e-5f);
        }
    }

    if (!P.final_flag) {
        unsigned short* hout = P.hout + (size_t)p * BTC;
#pragma unroll
        for (int mt = 0; mt < 4; ++mt)
#pragma unroll
            for (int rg = 0; rg < 4; ++rg) {
                const float m = mean_[mt * 4 + rg], rs = rstd_[mt * 4 + rg];
                const int grow = (bi << 6) + mt * 16 + lq * 4 + rg;
#pragma unroll
                for (int nt = 0; nt < 6; ++nt) {
                    const float v = (acc[mt * 6 + nt][rg] - m) * rs * gcol[nt] + becol[nt];
                    hout[(size_t)grow * C_ + nb + nt * 16 + ln] = f2bf(v);
                }
            }
    } else {
        __syncthreads();                       // rsum about to be reused
#pragma unroll
        for (int mt = 0; mt < 4; ++mt) {
#pragma unroll
            for (int rg = 0; rg < 4; ++rg) {
                const float m = mean_[mt * 4 + rg], rs = rstd_[mt * 4 + rg];
                float pr = 0.f;
#pragma unroll
                for (int nt = 0; nt < 6; ++nt)
                    pr += ((acc[mt * 6 + nt][rg] - m) * rs * gcol[nt] + becol[nt]) * wcol[nt];
#pragma unroll
                for (int off = 1; off < 16; off <<= 1)
                    pr += __shfl_xor(pr, off, 64);
                if (ln == mt * 4 + rg)
                    rsum[wave * 64 + mt * 16 + lq * 4 + rg] = pr;
            }
        }
        __syncthreads();
        if (tid < 64)
            P.pred[p][(bi << 6) + tid] =
                rsum[tid] + rsum[64 + tid] + rsum[128 + tid] + rsum[192 + tid] + P.bo[p][0];
    }
}

// ---------------------------------------------------------------------------
// Coalesced weight pack via LDS transpose. Grid: 216 blocks = 6 wsel x 36 r.
// Load w rows [r*32, r*32+32) x 384 cols coalesced (float4), transpose in
// LDS, write packed fragments as contiguous 16B stores.
// wpk[((r*4+wv)*6+nt)*512 + lane*8 + j] = w[(r*32 + lq*8 + j)*384 + wv*96+nt*16+ln]
// ---------------------------------------------------------------------------
#define WSS 388   /* LDS row stride (floats), 16B-aligned */
__global__ __launch_bounds__(256) void pack_w_kernel(
    const float* __restrict__ s0, const float* __restrict__ s1,
    const float* __restrict__ s2, const float* __restrict__ s3,
    const float* __restrict__ s4, const float* __restrict__ s5,
    unsigned short* __restrict__ dst)
{
    __shared__ float ws[32 * WSS];   // 48.5 KB
    const int blk  = blockIdx.x;
    const int wsel = blk / 36;
    const int r    = blk - wsel * 36;
    const float* src = wsel == 0 ? s0 : wsel == 1 ? s1 : wsel == 2 ? s2
                     : wsel == 3 ? s3 : wsel == 4 ? s4 : s5;
    const int tid = threadIdx.x;

    // coalesced load: 32 rows x 384 cols = 3072 float4
    const float* sb = src + (size_t)r * 32 * C_;
    for (int i4 = tid; i4 < 3072; i4 += 256) {
        const int k  = i4 / 96;
        const int n4 = i4 - k * 96;
        *(float4*)&ws[k * WSS + n4 * 4] = *(const float4*)(sb + (size_t)k * C_ + n4 * 4);
    }
    __syncthreads();

    // transpose-write: 1536 chunks of 8 bf16 (16 B), coalesced
    unsigned short* db = dst + (size_t)wsel * WPK1 + (size_t)r * 12288;
    for (int c = tid; c < 1536; c += 256) {
        const int lane = c & 63;
        const int wnt  = c >> 6;          // wv*6 + nt
        const int ln   = lane & 15;
        const int lq   = lane >> 4;
        const int n    = (wnt / 6) * 96 + (wnt % 6) * 16 + ln;
        ushort4 o0, o1;
        unsigned short e[8];
#pragma unroll
        for (int j = 0; j < 8; ++j)
            e[j] = f2bf(ws[(lq * 8 + j) * WSS + n]);
        o0 = make_ushort4(e[0], e[1], e[2], e[3]);
        o1 = make_ushort4(e[4], e[5], e[6], e[7]);
        *(ushort4*)(db + wnt * 512 + lane * 8)     = o0;
        *(ushort4*)(db + wnt * 512 + lane * 8 + 4) = o1;
    }
}

// Fused: per-batch cumsum of duration + per-frame packed gather index
// pk = t | plo<<10 | elo<<19 (or -1 if frame >= total); mel_len.
__global__ __launch_bounds__(256) void cumsum_idx_kernel(
    const int* __restrict__ dur,
    const float* __restrict__ pbins, const float* __restrict__ ptgt,
    const float* __restrict__ ebins, const float* __restrict__ etgt,
    int* __restrict__ xidx, float* __restrict__ mel_len)
{
    __shared__ int cs[T_];
    __shared__ int part[256];
    __shared__ float pb[NBINS_], eb[NBINS_];
    const int b = blockIdx.x;
    const int tid = threadIdx.x;
    if (tid < NBINS_) { pb[tid] = pbins[tid]; eb[tid] = ebins[tid]; }
    int l[4];
    int s = 0;
#pragma unroll
    for (int i = 0; i < 4; ++i) { l[i] = dur[(b << 10) + tid * 4 + i]; s += l[i]; }
    part[tid] = s;
    __syncthreads();
    for (int off = 1; off < 256; off <<= 1) {
        int u = 0;
        if (tid >= off) u = part[tid - off];
        __syncthreads();
        part[tid] += u;
        __syncthreads();
    }
    const int incl = part[tid];
    int run = incl - s;
#pragma unroll
    for (int i = 0; i < 4; ++i) {
        run += l[i];
        cs[tid * 4 + i] = run;
    }
    if (tid == 255) mel_len[b] = (float)incl;
    __syncthreads();
    const int total = cs[T_ - 1];
    for (int f = tid; f < MAXLEN_; f += 256) {
        int pk = -1;
        if (f < total) {
            int lo = 0, hi = T_;
            while (lo < hi) {
                const int mid = (lo + hi) >> 1;
                if (cs[mid] <= f) lo = mid + 1; else hi = mid;
            }
            const int t = lo > T_ - 1 ? T_ - 1 : lo;
            const int row = (b << 10) + t;
            const float ptg = ptgt[row];
            int plo = 0, phi = NBINS_;
            while (plo < phi) {
                const int mid = (plo + phi) >> 1;
                if (pb[mid] < ptg) plo = mid + 1; else phi = mid;
            }
            const float etg = etgt[row];
            int elo = 0, ehi = NBINS_;
            while (elo < ehi) {
                const int mid = (elo + ehi) >> 1;
                if (eb[mid] < etg) elo = mid + 1; else ehi = mid;
            }
            pk = t | (plo << 10) | (elo << 19);
        }
        xidx[(b << 11) + f] = pk;
    }
}

// out[b,frame,:] = pk<0 ? 0 : x[b,t,:] + pemb[plo] + eemb[elo]  (fp32 exact)
__global__ __launch_bounds__(256) void length_reg_kernel(
    const float* __restrict__ x, const int* __restrict__ xidx,
    const float* __restrict__ pemb, const float* __restrict__ eemb,
    float* __restrict__ out)
{
    const int g    = blockIdx.x * 256 + threadIdx.x;  // B*2048*96
    const int c4   = g % 96;
    const int rest = g / 96;
    const int frame = rest & (MAXLEN_ - 1);
    const int b     = rest >> 11;
    const int pk = xidx[(b << 11) + frame];
    float4 v = make_float4(0.f, 0.f, 0.f, 0.f);
    if (pk >= 0) {
        const int t   = pk & 1023;
        const int plo = (pk >> 10) & 511;
        const int elo = (pk >> 19) & 511;
        v = *(const float4*)(x + ((size_t)(b << 10) + t) * C_ + c4 * 4);
        const float4 pe = *(const float4*)(pemb + (size_t)plo * C_ + c4 * 4);
        const float4 ee = *(const float4*)(eemb + (size_t)elo * C_ + c4 * 4);
        v.x += pe.x + ee.x; v.y += pe.y + ee.y;
        v.z += pe.z + ee.z; v.w += pe.w + ee.w;
    }
    *(float4*)(out + (size_t)g * 4) = v;
}

extern "C" void kernel_launch(void* const* d_in, const int* in_sizes, int n_in,
                              void* d_out, int out_size, void* d_ws, size_t ws_size,
                              hipStream_t stream)
{
    const float* x        = (const float*)d_in[0];
    const int*   duration = (const int*)d_in[2];
    const float* P[3][10];
    for (int p = 0; p < 3; ++p)
        for (int q = 0; q < 10; ++q)
            P[p][q] = (const float*)d_in[4 + p * 10 + q];
    const float* pitch_bins    = (const float*)d_in[34];
    const float* energy_bins   = (const float*)d_in[35];
    const float* pitch_emb     = (const float*)d_in[36];
    const float* energy_emb    = (const float*)d_in[37];
    const float* pitch_target  = (const float*)d_in[38];
    const float* energy_target = (const float*)d_in[39];

    float* out_x      = (float*)d_out;                       // (B,2048,384)
    float* out_pitch  = out_x + (size_t)B_ * MAXLEN_ * C_;
    float* out_energy = out_pitch + B_ * T_;
    float* out_logdur = out_energy + B_ * T_;
    float* out_mellen = out_logdur + B_ * T_;

    // h1b (3 predictors, bf16) lives in the x_out region (75.5 MB of 100.7 MB,
    // dead before length_reg writes it)
    unsigned short* h1b = (unsigned short*)out_x;

    unsigned short* wpk = (unsigned short*)d_ws;             // 6*WPK1 bf16
    int* xidx = (int*)(wpk + (size_t)6 * WPK1);              // B*2048 ints

    const dim3 blk(256);

    pack_w_kernel<<<216, blk, 0, stream>>>(
        P[0][0], P[0][4], P[1][0], P[1][4], P[2][0], P[2][4], wpk);

    CvP P1;
    P1.xf = x; P1.xb = nullptr; P1.wpk = wpk;
    for (int p = 0; p < 3; ++p) {
        P1.bias[p]  = P[p][1];
        P1.gamma[p] = P[p][2];
        P1.beta[p]  = P[p][3];
        P1.wo[p]    = nullptr;
        P1.bo[p]    = nullptr;
        P1.pred[p]  = nullptr;
    }
    P1.hout = h1b;
    P1.pbins = pitch_bins; P1.pemb = pitch_emb; P1.ptgt = pitch_target;
    P1.final_flag = 0;

    CvP P2;
    P2.xf = nullptr; P2.xb = h1b; P2.wpk = wpk + (size_t)3 * WPK1;
    for (int p = 0; p < 3; ++p) {
        P2.bias[p]  = P[p][5];
        P2.gamma[p] = P[p][6];
        P2.beta[p]  = P[p][7];
        P2.wo[p]    = P[p][8];
        P2.bo[p]    = P[p][9];
    }
    P2.pred[0] = out_logdur; P2.pred[1] = out_pitch; P2.pred[2] = out_energy;
    P2.hout = nullptr;
    P2.pbins = nullptr; P2.pemb = nullptr; P2.ptgt = nullptr;
    P2.final_flag = 1;

    conv_mfma3<<<1536, blk, 0, stream>>>(P1);
    conv_mfma3<<<1536, blk, 0, stream>>>(P2);

    cumsum_idx_kernel<<<B_, blk, 0, stream>>>(
        duration, pitch_bins, pitch_target, energy_bins, energy_target,
        xidx, out_mellen);
    length_reg_kernel<<<24576, blk, 0, stream>>>(
        x, xidx, pitch_emb, energy_emb, out_x);
}